// Round 14
// baseline (271.926 us; speedup 1.0000x reference)
//
#include <hip/hip_runtime.h>
#include <float.h>

// B_=1024 windows, N=64, M=128, H=8, D=32, DIM=256, nW=256
// rel bias index: rel = n - m + 128 in [1,191]
// masks: wi in {0,1} -> mask_left[wi], wi in {254,255} -> mask_right[wi-254]

typedef __attribute__((ext_vector_type(8))) short bf16x8;
typedef __attribute__((ext_vector_type(4))) float f32x4;

static __device__ __forceinline__ unsigned int f2bf(float f) {
    unsigned int u = __float_as_uint(f);
    return (u + 0x7FFFu + ((u >> 16) & 1u)) >> 16;  // RNE
}
static __device__ __forceinline__ unsigned int pack2(float lo, float hi) {
    return f2bf(lo) | (f2bf(hi) << 16);
}
static __device__ __forceinline__ void glds16(const void* g, void* l) {
    __builtin_amdgcn_global_load_lds(
        (const __attribute__((address_space(1))) void*)g,
        (__attribute__((address_space(3))) void*)l, 16, 0, 0);
}

// All tile images: 128 rows/cols x 32 k bf16, 4096 shorts, row = 64 B,
// byte offset within row: (2*k) ^ ((row&3)<<4)  (XOR bits 4-5, in-row involution).
__device__ unsigned short g_Wi[262144];    // W images: q @0 (16 tiles), kv @65536 (32), proj @196608 (16)
__device__ unsigned short g_xq[16777216];  // x images (512 bm-tiles); later overwritten with attn-out images
__device__ unsigned short g_xb[33554432];  // x_ images (1024 bm-tiles)

__global__ __launch_bounds__(256) void prep_wt(
    const float* __restrict__ q_w, const float* __restrict__ kv_w, const float* __restrict__ proj_w)
{
    const int gid = blockIdx.x * 256 + threadIdx.x;
    int rel, ncs; const float* src;
    if (gid < 65536)       { rel = gid;          src = q_w;    ncs = 256; }
    else if (gid < 196608) { rel = gid - 65536;  src = kv_w;   ncs = 512; }
    else                   { rel = gid - 196608; src = proj_w; ncs = 256; }
    const int tl = rel >> 12, i = rel & 4095;      // tile = ct*8 + ks
    const int ct = tl >> 3,  ks = tl & 7;
    const int col = i >> 5,  si = i & 31;
    const int kl = ((2 * si) ^ ((col & 3) << 4)) >> 1;   // inverse swizzle -> source k
    g_Wi[gid] = (unsigned short)f2bf(src[(ks * 32 + kl) * ncs + ct * 128 + col]);
}

// cast x and x_ (f32) into bf16 swizzled tile images (16 shorts per thread)
__global__ __launch_bounds__(256) void cast_imgs(
    const float* __restrict__ x, const float* __restrict__ x_)
{
    const size_t u = (size_t)blockIdx.x * 256 + threadIdx.x;   // 0 .. 3145727
    const float* src; unsigned short* dst; size_t D;
    if (u < 1048576) { D = u * 16;             src = x;  dst = g_xq; }
    else             { D = (u - 1048576) * 16; src = x_; dst = g_xb; }
    const int bm = (int)(D >> 15), rem = (int)(D & 32767);
    const int ks = rem >> 12, i = rem & 4095;
    const int rr = i >> 5, si0 = i & 31;                 // si0 in {0,16}
    const float* srow = src + ((size_t)(bm * 128 + rr)) * 256 + ks * 32;
    const int swz = (rr & 3) << 4;
    #pragma unroll
    for (int g2 = 0; g2 < 2; ++g2) {
        const int si = si0 + 8 * g2;
        const int kl = ((2 * si) ^ swz) >> 1;
        const float4 a = *(const float4*)(srow + kl);
        const float4 b = *(const float4*)(srow + kl + 4);
        *(uint4*)(dst + D + 8 * g2) =
            make_uint4(pack2(a.x, a.y), pack2(a.z, a.w), pack2(b.x, b.y), pack2(b.z, b.w));
    }
}

// ---------- glds-pipelined MFMA GEMM: C[rows x NC] = A[rows x 256] @ W + bias ----------
// Tile 128x128, BK=32, dbuf 32 KB LDS -> 4 blocks/CU. 512 threads = 8 waves (2 row x 4 col).
// Staging = one width-16 global_load_lds per wave per operand (1 KB each), linear dest,
// swizzle baked into the source images. XCD swizzle keeps a row-tile's col-tiles on one XCD.
// VSPLIT (kv): col-tiles 0..1 -> K natural [row][256]; 2..3 -> V transposed vws[w][vcol][m].
template<int NC, int WT_OFF, int ASEL, bool F32OUT, bool VSPLIT>
__global__ __launch_bounds__(512) void gemm_g(
    const float* __restrict__ bias, void* __restrict__ Cout, unsigned short* __restrict__ Vout)
{
    constexpr int NBN = NC / 128;
    __shared__ __align__(16) unsigned short As[2][4096];
    __shared__ __align__(16) unsigned short Ws[2][4096];

    const int nbx = 8 * NBN;
    const int g = blockIdx.x / nbx, r = blockIdx.x % nbx;
    const int bn = r >> 3, bm = g * 8 + (r & 7);
    const size_t r0 = (size_t)bm * 128;
    const int c0 = bn * 128;

    const int t = threadIdx.x;
    const int wave = t >> 6, lane = t & 63;
    const int lr = lane & 15, hi = lane >> 4;
    const int rw = (wave >> 2) * 64, cw = (wave & 3) * 32;

    const unsigned short* Aimg = (ASEL == 0) ? g_xq : g_xb;
    const unsigned short* asrc = Aimg + ((size_t)bm << 15) + (wave << 9) + lane * 8;
    const unsigned short* wsrc = g_Wi + WT_OFF + ((size_t)(bn * 8) << 12) + (wave << 9) + lane * 8;

    f32x4 acc[4][2];
    #pragma unroll
    for (int i = 0; i < 4; ++i)
        #pragma unroll
        for (int j = 0; j < 2; ++j) acc[i][j] = (f32x4){0.f, 0.f, 0.f, 0.f};

#define GLDS(B, S)                                                         \
    {                                                                      \
        glds16(asrc + (S) * 4096, (unsigned short*)As[B] + (wave << 9));   \
        glds16(wsrc + (S) * 4096, (unsigned short*)Ws[B] + (wave << 9));   \
    }

#define COMPUTE(B)                                                                         \
    {                                                                                      \
        const char* Ab = (const char*)As[B];                                               \
        const char* Wb = (const char*)Ws[B];                                               \
        const int ko = (16 * hi) ^ ((lr & 3) << 4);                                        \
        bf16x8 af0 = *(const bf16x8*)(Ab + (rw +      lr) * 64 + ko);                      \
        bf16x8 af1 = *(const bf16x8*)(Ab + (rw + 16 + lr) * 64 + ko);                      \
        bf16x8 af2 = *(const bf16x8*)(Ab + (rw + 32 + lr) * 64 + ko);                      \
        bf16x8 af3 = *(const bf16x8*)(Ab + (rw + 48 + lr) * 64 + ko);                      \
        bf16x8 bg0 = *(const bf16x8*)(Wb + (cw +      lr) * 64 + ko);                      \
        bf16x8 bg1 = *(const bf16x8*)(Wb + (cw + 16 + lr) * 64 + ko);                      \
        acc[0][0] = __builtin_amdgcn_mfma_f32_16x16x32_bf16(af0, bg0, acc[0][0], 0, 0, 0); \
        acc[0][1] = __builtin_amdgcn_mfma_f32_16x16x32_bf16(af0, bg1, acc[0][1], 0, 0, 0); \
        acc[1][0] = __builtin_amdgcn_mfma_f32_16x16x32_bf16(af1, bg0, acc[1][0], 0, 0, 0); \
        acc[1][1] = __builtin_amdgcn_mfma_f32_16x16x32_bf16(af1, bg1, acc[1][1], 0, 0, 0); \
        acc[2][0] = __builtin_amdgcn_mfma_f32_16x16x32_bf16(af2, bg0, acc[2][0], 0, 0, 0); \
        acc[2][1] = __builtin_amdgcn_mfma_f32_16x16x32_bf16(af2, bg1, acc[2][1], 0, 0, 0); \
        acc[3][0] = __builtin_amdgcn_mfma_f32_16x16x32_bf16(af3, bg0, acc[3][0], 0, 0, 0); \
        acc[3][1] = __builtin_amdgcn_mfma_f32_16x16x32_bf16(af3, bg1, acc[3][1], 0, 0, 0); \
    }

    GLDS(0, 0);
    __syncthreads();                       // vmcnt(0) drain -> buf0 ready

    #pragma unroll 8
    for (int s = 0; s < 8; ++s) {
        if (s < 7) GLDS((s + 1) & 1, s + 1);   // async into other buffer
        COMPUTE(s & 1);
        if (s < 7) __syncthreads();            // drains glds; publishes buf s+1
    }

#undef GLDS
#undef COMPUTE

    // epilogue: row = r0+rw+i*16+4*hi+q, col = c0+cw+bj*16+lr
    #pragma unroll
    for (int i = 0; i < 4; ++i) {
        #pragma unroll
        for (int bj = 0; bj < 2; ++bj) {
            const int col = c0 + cw + bj * 16 + lr;
            const float bb = bias[col];
            if (VSPLIT && c0 >= 256) {
                const int vcol = col - 256;
                const int m0 = rw + i * 16 + 4 * hi;
                const unsigned int lo = pack2(acc[i][bj][0] + bb, acc[i][bj][1] + bb);
                const unsigned int h2 = pack2(acc[i][bj][2] + bb, acc[i][bj][3] + bb);
                *(uint2*)(Vout + (size_t)bm * 32768 + vcol * 128 + m0) = make_uint2(lo, h2);
            } else if (VSPLIT) {
                #pragma unroll
                for (int q = 0; q < 4; ++q) {
                    const size_t row = r0 + rw + i * 16 + 4 * hi + q;
                    ((unsigned short*)Cout)[row * 256 + col] = (unsigned short)f2bf(acc[i][bj][q] + bb);
                }
            } else {
                #pragma unroll
                for (int q = 0; q < 4; ++q) {
                    const size_t row = r0 + rw + i * 16 + 4 * hi + q;
                    const float val = acc[i][bj][q] + bb;
                    if (F32OUT) ((float*)Cout)[row * NC + col] = val;
                    else        ((unsigned short*)Cout)[row * NC + col] = (unsigned short)f2bf(val);
                }
            }
        }
    }
}

// ---------- fused MFMA attention: one block per WINDOW, loop over 8 heads ----------
// K natural from kws, V pre-transposed from vws. Writes attn-out as bf16 TILE IMAGES
// into g_xq (x images are dead after q-gemm) for the glds proj GEMM.
__global__ __launch_bounds__(256) void attn_fused(
    const unsigned short* __restrict__ qbf, const unsigned short* __restrict__ kws,
    const unsigned short* __restrict__ vws, const float* __restrict__ bias_table,
    const int* __restrict__ mask_left, const int* __restrict__ mask_right)
{
    __shared__ __align__(16) unsigned short Qn[64 * 32];    // [n][d] natural
    __shared__ __align__(16) unsigned short Kn[128 * 32];   // [m][d] natural
    __shared__ __align__(16) unsigned short Vt[32 * 128];   // [d][m], swizzled ^((d&7)<<4)
    __shared__ __align__(16) unsigned short Pn[64 * 128];   // [n][m], swizzled ^((n&7)<<4)
    __shared__ float ballT[8 * 192];                        // bias table [h][rel]

    const int w = blockIdx.x;
    const int t = threadIdx.x;
    const int wave = t >> 6, lane = t & 63;
    const int lr = lane & 15, hi = lane >> 4;
    const int n0w = wave * 16;

    for (int i = t; i < 1536; i += 256) {
        const int hh = i / 192, rr = i - hh * 192;
        ballT[i] = bias_table[rr * 8 + hh];
    }

    const int wi = w & 255;
    const int* mbase = nullptr;
    if (wi < 2) mbase = mask_left + wi * (64 * 128);
    else if (wi >= 254) mbase = mask_right + (wi - 254) * (64 * 128);

    const float scale = 0.17677669529663687f;  // 32^-0.5

    for (int h = 0; h < 8; ++h) {
        __syncthreads();   // prior iteration's LDS reads complete (and ballT before first use)
        {   // stage Q head-slice: [64][32]
            const int n = t >> 2, dq = t & 3;
            const uint4 v = *(const uint4*)(qbf + ((size_t)(w * 64 + n)) * 256 + h * 32 + dq * 8);
            *(uint4*)((char*)Qn + n * 64 + dq * 16) = v;
        }
        #pragma unroll
        for (int i = 0; i < 2; ++i) {   // stage K: [128][32] natural
            const int m = (t >> 2) + 64 * i, dq = t & 3;
            const uint4 v = *(const uint4*)(kws + ((size_t)(w * 128 + m)) * 256 + h * 32 + dq * 8);
            *(uint4*)((char*)Kn + m * 64 + dq * 16) = v;
        }
        {   // stage V: contiguous 8KB from vws -> swizzled Vt (pure uint4 copies)
            const unsigned short* vsrc = vws + (size_t)w * 32768 + h * 32 * 128;
            #pragma unroll
            for (int i = 0; i < 2; ++i) {
                const int u = t + i * 256;        // 16B units, 0..511
                const int d = u >> 4, mseg = u & 15;
                const uint4 vv = *(const uint4*)(vsrc + d * 128 + mseg * 8);
                *(uint4*)((char*)Vt + d * 256 + ((mseg * 16) ^ ((d & 7) << 4))) = vv;
            }
        }
        __syncthreads();

        // S = Q K^T : wave handles rows n0w..n0w+15, all 128 cols
        const bf16x8 qa = *(const bf16x8*)((char*)Qn + (n0w + lr) * 64 + 16 * hi);
        f32x4 sacc[8];
        #pragma unroll
        for (int mj = 0; mj < 8; ++mj) {
            sacc[mj] = (f32x4){0.f, 0.f, 0.f, 0.f};
            const bf16x8 kb = *(const bf16x8*)((char*)Kn + (mj * 16 + lr) * 64 + 16 * hi);
            sacc[mj] = __builtin_amdgcn_mfma_f32_16x16x32_bf16(qa, kb, sacc[mj], 0, 0, 0);
        }

        // epilogue on C-layout: row n = n0w + 4*hi + q, col m = 16*mj + lr
        const float* bh = ballT + h * 192;
        #pragma unroll
        for (int mj = 0; mj < 8; ++mj) {
            const int m = 16 * mj + lr;
            #pragma unroll
            for (int q = 0; q < 4; ++q) {
                const int n = n0w + 4 * hi + q;
                sacc[mj][q] = fmaf(sacc[mj][q], scale, bh[n - m + 128]);
            }
        }
        if (mbase) {
            #pragma unroll
            for (int mj = 0; mj < 8; ++mj) {
                const int m = 16 * mj + lr;
                #pragma unroll
                for (int q = 0; q < 4; ++q) {
                    const int n = n0w + 4 * hi + q;
                    if (mbase[n * 128 + m] == 1) sacc[mj][q] = -FLT_MAX;
                }
            }
        }

        // softmax over m (per row): row lives in 16 lanes sharing hi -> shfl_xor 1,2,4,8
        float inv[4];
        #pragma unroll
        for (int q = 0; q < 4; ++q) {
            float mx = sacc[0][q];
            #pragma unroll
            for (int mj = 1; mj < 8; ++mj) mx = fmaxf(mx, sacc[mj][q]);
            mx = fmaxf(mx, __shfl_xor(mx, 1));
            mx = fmaxf(mx, __shfl_xor(mx, 2));
            mx = fmaxf(mx, __shfl_xor(mx, 4));
            mx = fmaxf(mx, __shfl_xor(mx, 8));
            float sm = 0.f;
            #pragma unroll
            for (int mj = 0; mj < 8; ++mj) {
                sacc[mj][q] = __expf(sacc[mj][q] - mx);
                sm += sacc[mj][q];
            }
            sm += __shfl_xor(sm, 1);
            sm += __shfl_xor(sm, 2);
            sm += __shfl_xor(sm, 4);
            sm += __shfl_xor(sm, 8);
            inv[q] = 1.0f / sm;
        }

        // write unnormalized P bf16 to Pn (pair even/odd lanes -> u32 stores); wave-local rows
        #pragma unroll
        for (int mj = 0; mj < 8; ++mj) {
            #pragma unroll
            for (int q = 0; q < 4; ++q) {
                const float pv = sacc[mj][q];
                const float po = __shfl_xor(pv, 1);
                if (!(lane & 1)) {
                    const int n = n0w + 4 * hi + q;
                    const int m = 16 * mj + lr;   // even
                    *(unsigned int*)((char*)Pn + n * 256 + ((2 * m) ^ ((n & 7) << 4))) =
                        f2bf(pv) | (f2bf(po) << 16);
                }
            }
        }
        // no barrier needed: each wave reads only its own Pn rows

        // O = P V : rows n0w..+15, cols d 0..31 (j=0,1)
        f32x4 oacc[2];
        oacc[0] = (f32x4){0.f, 0.f, 0.f, 0.f};
        oacc[1] = (f32x4){0.f, 0.f, 0.f, 0.f};
        const int nA = n0w + lr;                 // A-frag row
        const int swzA = (nA & 7) << 4;
        #pragma unroll
        for (int kk = 0; kk < 4; ++kk) {
            const bf16x8 pa = *(const bf16x8*)((char*)Pn + nA * 256 + ((64 * kk + 16 * hi) ^ swzA));
            #pragma unroll
            for (int j = 0; j < 2; ++j) {
                const int d = j * 16 + lr;
                const bf16x8 vb = *(const bf16x8*)((char*)Vt + d * 256 + ((64 * kk + 16 * hi) ^ ((d & 7) << 4)));
                oacc[j] = __builtin_amdgcn_mfma_f32_16x16x32_bf16(pa, vb, oacc[j], 0, 0, 0);
            }
        }
        // store bf16 attn-out as tile image into g_xq: global row R = w*64+n, col c = h*32+j*16+lr
        #pragma unroll
        for (int j = 0; j < 2; ++j) {
            #pragma unroll
            for (int q = 0; q < 4; ++q) {
                const int n = n0w + 4 * hi + q;
                const int R = w * 64 + n;
                const int bmO = R >> 7, rr = R & 127;
                const int c31 = j * 16 + lr;
                const int si = c31 ^ ((rr & 3) << 3);
                g_xq[((size_t)bmO << 15) + (h << 12) + rr * 32 + si] =
                    (unsigned short)f2bf(oacc[j][q] * inv[q]);
            }
        }
    }
}

extern "C" void kernel_launch(void* const* d_in, const int* in_sizes, int n_in,
                              void* d_out, int out_size, void* d_ws, size_t ws_size,
                              hipStream_t stream)
{
    const float* x      = (const float*)d_in[0];   // (1024,64,256) f32
    const float* x_     = (const float*)d_in[1];   // (1024,128,256) f32
    const int*   mask_l = (const int*)d_in[2];
    const int*   mask_r = (const int*)d_in[3];
    const float* q_w    = (const float*)d_in[5];
    const float* q_b    = (const float*)d_in[6];
    const float* kv_w   = (const float*)d_in[7];
    const float* kv_b   = (const float*)d_in[8];
    const float* proj_w = (const float*)d_in[9];
    const float* proj_b = (const float*)d_in[10];
    const float* bias_t = (const float*)d_in[11];  // (192,8)

    // ws: qbf [65536][256] bf16 (32 MiB) | kws [131072][256] bf16 (64 MiB, K natural)
    //   | vws [1024][256][128] bf16 (64 MiB, V transposed per window)
    unsigned short* qbf = (unsigned short*)d_ws;
    unsigned short* kws = qbf + (size_t)65536 * 256;
    unsigned short* vws = kws + (size_t)131072 * 256;
    float* out = (float*)d_out;

    prep_wt<<<1024, 256, 0, stream>>>(q_w, kv_w, proj_w);
    cast_imgs<<<12288, 256, 0, stream>>>(x, x_);
    gemm_g<256, 0,      0, false, false><<<1024, 512, 0, stream>>>(q_b,    qbf, nullptr);
    gemm_g<512, 65536,  1, false, true ><<<4096, 512, 0, stream>>>(kv_b,   kws, vws);
    attn_fused<<<1024, 256, 0, stream>>>(qbf, kws, vws, bias_t, mask_l, mask_r);
    gemm_g<256, 196608, 0, true,  false><<<1024, 512, 0, stream>>>(proj_b, out, nullptr);
}

// Round 17
// 268.675 us; speedup vs baseline: 1.0121x; 1.0121x over previous
//
#include <hip/hip_runtime.h>
#include <float.h>

// B_=1024 windows, N=64, M=128, H=8, D=32, DIM=256, nW=256
// rel bias index: rel = n - m + 128 in [1,191]
// masks: wi in {0,1} -> mask_left[wi], wi in {254,255} -> mask_right[wi-254]

typedef __attribute__((ext_vector_type(8))) short bf16x8;
typedef __attribute__((ext_vector_type(4))) float f32x4;

static __device__ __forceinline__ unsigned int f2bf(float f) {
    unsigned int u = __float_as_uint(f);
    return (u + 0x7FFFu + ((u >> 16) & 1u)) >> 16;  // RNE
}
static __device__ __forceinline__ unsigned int pack2(float lo, float hi) {
    return f2bf(lo) | (f2bf(hi) << 16);
}
static __device__ __forceinline__ void glds16(const void* g, void* l) {
    __builtin_amdgcn_global_load_lds(
        (const __attribute__((address_space(1))) void*)g,
        (__attribute__((address_space(3))) void*)l, 16, 0, 0);
}

// All tile images: 128 rows/cols x 32 k bf16, 4096 shorts, row = 64 B,
// byte offset within row: (2*k) ^ ((row&3)<<4)  (XOR bits 4-5, in-row involution).
__device__ unsigned short g_Wi[262144];    // W images: q @0 (16 tiles), kv @65536 (32), proj @196608 (16)
__device__ unsigned short g_xq[16777216];  // x images (512 bm-tiles); later overwritten with attn-out images
__device__ unsigned short g_xb[33554432];  // x_ images (1024 bm-tiles)

__global__ __launch_bounds__(256) void prep_wt(
    const float* __restrict__ q_w, const float* __restrict__ kv_w, const float* __restrict__ proj_w)
{
    const int gid = blockIdx.x * 256 + threadIdx.x;
    int rel, ncs; const float* src;
    if (gid < 65536)       { rel = gid;          src = q_w;    ncs = 256; }
    else if (gid < 196608) { rel = gid - 65536;  src = kv_w;   ncs = 512; }
    else                   { rel = gid - 196608; src = proj_w; ncs = 256; }
    const int tl = rel >> 12, i = rel & 4095;      // tile = ct*8 + ks
    const int ct = tl >> 3,  ks = tl & 7;
    const int col = i >> 5,  si = i & 31;
    const int kl = ((2 * si) ^ ((col & 3) << 4)) >> 1;   // inverse swizzle -> source k
    g_Wi[gid] = (unsigned short)f2bf(src[(ks * 32 + kl) * ncs + ct * 128 + col]);
}

// cast x and x_ (f32) into bf16 swizzled tile images via LDS-staged transpose:
// global reads and writes are fully linear; the permutation happens in LDS.
__global__ __launch_bounds__(256) void cast_imgs(
    const float* __restrict__ x, const float* __restrict__ x_)
{
    __shared__ __align__(16) unsigned short L[32768];   // one bm-tile image (64 KB)
    const int b = blockIdx.x;
    const float* src; unsigned short* dst; int bm;
    if (b < 512) { bm = b;       src = x;  dst = g_xq; }
    else         { bm = b - 512; src = x_; dst = g_xb; }
    const int t = threadIdx.x;

    // phase 1: linear f32 read (512 B/thread contiguous), convert, scatter into LDS image
    const int rr = t >> 1, k0 = (t & 1) * 128;
    const float* srow = src + ((size_t)bm * 128 + rr) * 256 + k0;
    const int swz = (rr & 3) << 4;
    #pragma unroll
    for (int g2 = 0; g2 < 16; ++g2) {
        const int k = k0 + g2 * 8;
        const float4 a = *(const float4*)(srow + g2 * 8);
        const float4 c = *(const float4*)(srow + g2 * 8 + 4);
        const int ks = k >> 5, sk = k & 31;
        char* lp = (char*)L + (ks * 128 + rr) * 64 + ((2 * sk) ^ swz);
        *(uint4*)lp = make_uint4(pack2(a.x, a.y), pack2(a.z, a.w),
                                 pack2(c.x, c.y), pack2(c.z, c.w));
    }
    __syncthreads();

    // phase 2: linear stream LDS image -> global (full 4096 uint4 = 64 KB)
    const uint4* Ls = (const uint4*)L;
    uint4* gout = (uint4*)(dst + ((size_t)bm << 15));
    #pragma unroll
    for (int g2 = 0; g2 < 16; ++g2)
        gout[t + g2 * 256] = Ls[t + g2 * 256];
}

// ---------- glds-pipelined MFMA GEMM: C[rows x NC] = A[rows x 256] @ W + bias ----------
// Tile 128x128, BK=32, dbuf 32 KB LDS -> 4 blocks/CU. 512 threads = 8 waves (2 row x 4 col).
// Staging = one width-16 global_load_lds per wave per operand (1 KB each), linear dest,
// swizzle baked into the source images. XCD swizzle keeps a row-tile's col-tiles on one XCD.
// VSPLIT (kv): col-tiles 0..1 -> K natural [row][256]; 2..3 -> V transposed vws[w][vcol][m].
template<int NC, int WT_OFF, int ASEL, bool F32OUT, bool VSPLIT>
__global__ __launch_bounds__(512) void gemm_g(
    const float* __restrict__ bias, void* __restrict__ Cout, unsigned short* __restrict__ Vout)
{
    constexpr int NBN = NC / 128;
    __shared__ __align__(16) unsigned short As[2][4096];
    __shared__ __align__(16) unsigned short Ws[2][4096];

    const int nbx = 8 * NBN;
    const int g = blockIdx.x / nbx, r = blockIdx.x % nbx;
    const int bn = r >> 3, bm = g * 8 + (r & 7);
    const size_t r0 = (size_t)bm * 128;
    const int c0 = bn * 128;

    const int t = threadIdx.x;
    const int wave = t >> 6, lane = t & 63;
    const int lr = lane & 15, hi = lane >> 4;
    const int rw = (wave >> 2) * 64, cw = (wave & 3) * 32;

    const unsigned short* Aimg = (ASEL == 0) ? g_xq : g_xb;
    const unsigned short* asrc = Aimg + ((size_t)bm << 15) + (wave << 9) + lane * 8;
    const unsigned short* wsrc = g_Wi + WT_OFF + ((size_t)(bn * 8) << 12) + (wave << 9) + lane * 8;

    f32x4 acc[4][2];
    #pragma unroll
    for (int i = 0; i < 4; ++i)
        #pragma unroll
        for (int j = 0; j < 2; ++j) acc[i][j] = (f32x4){0.f, 0.f, 0.f, 0.f};

#define GLDS(B, S)                                                         \
    {                                                                      \
        glds16(asrc + (S) * 4096, (unsigned short*)As[B] + (wave << 9));   \
        glds16(wsrc + (S) * 4096, (unsigned short*)Ws[B] + (wave << 9));   \
    }

#define COMPUTE(B)                                                                         \
    {                                                                                      \
        const char* Ab = (const char*)As[B];                                               \
        const char* Wb = (const char*)Ws[B];                                               \
        const int ko = (16 * hi) ^ ((lr & 3) << 4);                                        \
        bf16x8 af0 = *(const bf16x8*)(Ab + (rw +      lr) * 64 + ko);                      \
        bf16x8 af1 = *(const bf16x8*)(Ab + (rw + 16 + lr) * 64 + ko);                      \
        bf16x8 af2 = *(const bf16x8*)(Ab + (rw + 32 + lr) * 64 + ko);                      \
        bf16x8 af3 = *(const bf16x8*)(Ab + (rw + 48 + lr) * 64 + ko);                      \
        bf16x8 bg0 = *(const bf16x8*)(Wb + (cw +      lr) * 64 + ko);                      \
        bf16x8 bg1 = *(const bf16x8*)(Wb + (cw + 16 + lr) * 64 + ko);                      \
        acc[0][0] = __builtin_amdgcn_mfma_f32_16x16x32_bf16(af0, bg0, acc[0][0], 0, 0, 0); \
        acc[0][1] = __builtin_amdgcn_mfma_f32_16x16x32_bf16(af0, bg1, acc[0][1], 0, 0, 0); \
        acc[1][0] = __builtin_amdgcn_mfma_f32_16x16x32_bf16(af1, bg0, acc[1][0], 0, 0, 0); \
        acc[1][1] = __builtin_amdgcn_mfma_f32_16x16x32_bf16(af1, bg1, acc[1][1], 0, 0, 0); \
        acc[2][0] = __builtin_amdgcn_mfma_f32_16x16x32_bf16(af2, bg0, acc[2][0], 0, 0, 0); \
        acc[2][1] = __builtin_amdgcn_mfma_f32_16x16x32_bf16(af2, bg1, acc[2][1], 0, 0, 0); \
        acc[3][0] = __builtin_amdgcn_mfma_f32_16x16x32_bf16(af3, bg0, acc[3][0], 0, 0, 0); \
        acc[3][1] = __builtin_amdgcn_mfma_f32_16x16x32_bf16(af3, bg1, acc[3][1], 0, 0, 0); \
    }

    GLDS(0, 0);
    __syncthreads();                       // vmcnt(0) drain -> buf0 ready

    #pragma unroll 8
    for (int s = 0; s < 8; ++s) {
        if (s < 7) GLDS((s + 1) & 1, s + 1);   // async into other buffer
        COMPUTE(s & 1);
        if (s < 7) __syncthreads();            // drains glds; publishes buf s+1
    }

#undef GLDS
#undef COMPUTE

    // epilogue: row = r0+rw+i*16+4*hi+q, col = c0+cw+bj*16+lr
    #pragma unroll
    for (int i = 0; i < 4; ++i) {
        #pragma unroll
        for (int bj = 0; bj < 2; ++bj) {
            const int col = c0 + cw + bj * 16 + lr;
            const float bb = bias[col];
            if (VSPLIT && c0 >= 256) {
                const int vcol = col - 256;
                const int m0 = rw + i * 16 + 4 * hi;
                const unsigned int lo = pack2(acc[i][bj][0] + bb, acc[i][bj][1] + bb);
                const unsigned int h2 = pack2(acc[i][bj][2] + bb, acc[i][bj][3] + bb);
                *(uint2*)(Vout + (size_t)bm * 32768 + vcol * 128 + m0) = make_uint2(lo, h2);
            } else if (VSPLIT) {
                #pragma unroll
                for (int q = 0; q < 4; ++q) {
                    const size_t row = r0 + rw + i * 16 + 4 * hi + q;
                    ((unsigned short*)Cout)[row * 256 + col] = (unsigned short)f2bf(acc[i][bj][q] + bb);
                }
            } else {
                #pragma unroll
                for (int q = 0; q < 4; ++q) {
                    const size_t row = r0 + rw + i * 16 + 4 * hi + q;
                    const float val = acc[i][bj][q] + bb;
                    if (F32OUT) ((float*)Cout)[row * NC + col] = val;
                    else        ((unsigned short*)Cout)[row * NC + col] = (unsigned short)f2bf(val);
                }
            }
        }
    }
}

// ---------- fused MFMA attention: one block per WINDOW, loop over 8 heads ----------
// K natural from kws, V pre-transposed from vws. Writes attn-out as bf16 TILE IMAGES
// into g_xq (x images are dead after q-gemm) for the glds proj GEMM.
__global__ __launch_bounds__(256) void attn_fused(
    const unsigned short* __restrict__ qbf, const unsigned short* __restrict__ kws,
    const unsigned short* __restrict__ vws, const float* __restrict__ bias_table,
    const int* __restrict__ mask_left, const int* __restrict__ mask_right)
{
    __shared__ __align__(16) unsigned short Qn[64 * 32];    // [n][d] natural
    __shared__ __align__(16) unsigned short Kn[128 * 32];   // [m][d] natural
    __shared__ __align__(16) unsigned short Vt[32 * 128];   // [d][m], swizzled ^((d&7)<<4)
    __shared__ __align__(16) unsigned short Pn[64 * 128];   // [n][m], swizzled ^((n&7)<<4)
    __shared__ float ballT[8 * 192];                        // bias table [h][rel]

    const int w = blockIdx.x;
    const int t = threadIdx.x;
    const int wave = t >> 6, lane = t & 63;
    const int lr = lane & 15, hi = lane >> 4;
    const int n0w = wave * 16;

    for (int i = t; i < 1536; i += 256) {
        const int hh = i / 192, rr = i - hh * 192;
        ballT[i] = bias_table[rr * 8 + hh];
    }

    const int wi = w & 255;
    const int* mbase = nullptr;
    if (wi < 2) mbase = mask_left + wi * (64 * 128);
    else if (wi >= 254) mbase = mask_right + (wi - 254) * (64 * 128);

    const float scale = 0.17677669529663687f;  // 32^-0.5

    for (int h = 0; h < 8; ++h) {
        __syncthreads();   // prior iteration's LDS reads complete (and ballT before first use)
        {   // stage Q head-slice: [64][32]
            const int n = t >> 2, dq = t & 3;
            const uint4 v = *(const uint4*)(qbf + ((size_t)(w * 64 + n)) * 256 + h * 32 + dq * 8);
            *(uint4*)((char*)Qn + n * 64 + dq * 16) = v;
        }
        #pragma unroll
        for (int i = 0; i < 2; ++i) {   // stage K: [128][32] natural
            const int m = (t >> 2) + 64 * i, dq = t & 3;
            const uint4 v = *(const uint4*)(kws + ((size_t)(w * 128 + m)) * 256 + h * 32 + dq * 8);
            *(uint4*)((char*)Kn + m * 64 + dq * 16) = v;
        }
        {   // stage V: contiguous 8KB from vws -> swizzled Vt (pure uint4 copies)
            const unsigned short* vsrc = vws + (size_t)w * 32768 + h * 32 * 128;
            #pragma unroll
            for (int i = 0; i < 2; ++i) {
                const int u = t + i * 256;        // 16B units, 0..511
                const int d = u >> 4, mseg = u & 15;
                const uint4 vv = *(const uint4*)(vsrc + d * 128 + mseg * 8);
                *(uint4*)((char*)Vt + d * 256 + ((mseg * 16) ^ ((d & 7) << 4))) = vv;
            }
        }
        __syncthreads();

        // S = Q K^T : wave handles rows n0w..n0w+15, all 128 cols
        const bf16x8 qa = *(const bf16x8*)((char*)Qn + (n0w + lr) * 64 + 16 * hi);
        f32x4 sacc[8];
        #pragma unroll
        for (int mj = 0; mj < 8; ++mj) {
            sacc[mj] = (f32x4){0.f, 0.f, 0.f, 0.f};
            const bf16x8 kb = *(const bf16x8*)((char*)Kn + (mj * 16 + lr) * 64 + 16 * hi);
            sacc[mj] = __builtin_amdgcn_mfma_f32_16x16x32_bf16(qa, kb, sacc[mj], 0, 0, 0);
        }

        // epilogue on C-layout: row n = n0w + 4*hi + q, col m = 16*mj + lr
        const float* bh = ballT + h * 192;
        #pragma unroll
        for (int mj = 0; mj < 8; ++mj) {
            const int m = 16 * mj + lr;
            #pragma unroll
            for (int q = 0; q < 4; ++q) {
                const int n = n0w + 4 * hi + q;
                sacc[mj][q] = fmaf(sacc[mj][q], scale, bh[n - m + 128]);
            }
        }
        if (mbase) {
            #pragma unroll
            for (int mj = 0; mj < 8; ++mj) {
                const int m = 16 * mj + lr;
                #pragma unroll
                for (int q = 0; q < 4; ++q) {
                    const int n = n0w + 4 * hi + q;
                    if (mbase[n * 128 + m] == 1) sacc[mj][q] = -FLT_MAX;
                }
            }
        }

        // softmax over m (per row): row lives in 16 lanes sharing hi -> shfl_xor 1,2,4,8
        float inv[4];
        #pragma unroll
        for (int q = 0; q < 4; ++q) {
            float mx = sacc[0][q];
            #pragma unroll
            for (int mj = 1; mj < 8; ++mj) mx = fmaxf(mx, sacc[mj][q]);
            mx = fmaxf(mx, __shfl_xor(mx, 1));
            mx = fmaxf(mx, __shfl_xor(mx, 2));
            mx = fmaxf(mx, __shfl_xor(mx, 4));
            mx = fmaxf(mx, __shfl_xor(mx, 8));
            float sm = 0.f;
            #pragma unroll
            for (int mj = 0; mj < 8; ++mj) {
                sacc[mj][q] = __expf(sacc[mj][q] - mx);
                sm += sacc[mj][q];
            }
            sm += __shfl_xor(sm, 1);
            sm += __shfl_xor(sm, 2);
            sm += __shfl_xor(sm, 4);
            sm += __shfl_xor(sm, 8);
            inv[q] = 1.0f / sm;
        }

        // write unnormalized P bf16 to Pn (pair even/odd lanes -> u32 stores); wave-local rows
        #pragma unroll
        for (int mj = 0; mj < 8; ++mj) {
            #pragma unroll
            for (int q = 0; q < 4; ++q) {
                const float pv = sacc[mj][q];
                const float po = __shfl_xor(pv, 1);
                if (!(lane & 1)) {
                    const int n = n0w + 4 * hi + q;
                    const int m = 16 * mj + lr;   // even
                    *(unsigned int*)((char*)Pn + n * 256 + ((2 * m) ^ ((n & 7) << 4))) =
                        f2bf(pv) | (f2bf(po) << 16);
                }
            }
        }
        // no barrier needed: each wave reads only its own Pn rows

        // O = P V : rows n0w..+15, cols d 0..31 (j=0,1)
        f32x4 oacc[2];
        oacc[0] = (f32x4){0.f, 0.f, 0.f, 0.f};
        oacc[1] = (f32x4){0.f, 0.f, 0.f, 0.f};
        const int nA = n0w + lr;                 // A-frag row
        const int swzA = (nA & 7) << 4;
        #pragma unroll
        for (int kk = 0; kk < 4; ++kk) {
            const bf16x8 pa = *(const bf16x8*)((char*)Pn + nA * 256 + ((64 * kk + 16 * hi) ^ swzA));
            #pragma unroll
            for (int j = 0; j < 2; ++j) {
                const int d = j * 16 + lr;
                const bf16x8 vb = *(const bf16x8*)((char*)Vt + d * 256 + ((64 * kk + 16 * hi) ^ ((d & 7) << 4)));
                oacc[j] = __builtin_amdgcn_mfma_f32_16x16x32_bf16(pa, vb, oacc[j], 0, 0, 0);
            }
        }
        // store bf16 attn-out as tile image into g_xq: global row R = w*64+n, col c = h*32+j*16+lr
        #pragma unroll
        for (int j = 0; j < 2; ++j) {
            #pragma unroll
            for (int q = 0; q < 4; ++q) {
                const int n = n0w + 4 * hi + q;
                const int R = w * 64 + n;
                const int bmO = R >> 7, rr = R & 127;
                const int c31 = j * 16 + lr;
                const int si = c31 ^ ((rr & 3) << 3);
                g_xq[((size_t)bmO << 15) + (h << 12) + rr * 32 + si] =
                    (unsigned short)f2bf(oacc[j][q] * inv[q]);
            }
        }
    }
}

extern "C" void kernel_launch(void* const* d_in, const int* in_sizes, int n_in,
                              void* d_out, int out_size, void* d_ws, size_t ws_size,
                              hipStream_t stream)
{
    const float* x      = (const float*)d_in[0];   // (1024,64,256) f32
    const float* x_     = (const float*)d_in[1];   // (1024,128,256) f32
    const int*   mask_l = (const int*)d_in[2];
    const int*   mask_r = (const int*)d_in[3];
    const float* q_w    = (const float*)d_in[5];
    const float* q_b    = (const float*)d_in[6];
    const float* kv_w   = (const float*)d_in[7];
    const float* kv_b   = (const float*)d_in[8];
    const float* proj_w = (const float*)d_in[9];
    const float* proj_b = (const float*)d_in[10];
    const float* bias_t = (const float*)d_in[11];  // (192,8)

    // ws: qbf [65536][256] bf16 (32 MiB) | kws [131072][256] bf16 (64 MiB, K natural)
    //   | vws [1024][256][128] bf16 (64 MiB, V transposed per window)
    unsigned short* qbf = (unsigned short*)d_ws;
    unsigned short* kws = qbf + (size_t)65536 * 256;
    unsigned short* vws = kws + (size_t)131072 * 256;
    float* out = (float*)d_out;

    prep_wt<<<1024, 256, 0, stream>>>(q_w, kv_w, proj_w);
    cast_imgs<<<1536, 256, 0, stream>>>(x, x_);
    gemm_g<256, 0,      0, false, false><<<1024, 512, 0, stream>>>(q_b,    qbf, nullptr);
    gemm_g<512, 65536,  1, false, true ><<<4096, 512, 0, stream>>>(kv_b,   kws, vws);
    attn_fused<<<1024, 256, 0, stream>>>(qbf, kws, vws, bias_t, mask_l, mask_r);
    gemm_g<256, 196608, 0, true,  false><<<1024, 512, 0, stream>>>(proj_b, out, nullptr);
}